// Round 1
// baseline (1076.286 us; speedup 1.0000x reference)
//
#include <hip/hip_runtime.h>

#define N_NODES 100000
#define N_EDGES 640000
#define D 128
#define NLAYERS 4

// ---------------- CSR build ----------------
__global__ void count_kernel(const int* __restrict__ edge, int* __restrict__ cnt) {
    int e = blockIdx.x * 256 + threadIdx.x;
    if (e < N_EDGES) {
        atomicAdd(&cnt[edge[N_EDGES + e]], 1);
    }
}

__global__ void scan_local(const int* __restrict__ cnt, int* __restrict__ rp,
                           int* __restrict__ bsum) {
    __shared__ int tsum[256];
    int t = threadIdx.x;
    int base = blockIdx.x * 1024 + t * 4;
    int v[4];
#pragma unroll
    for (int j = 0; j < 4; ++j) {
        int i = base + j;
        v[j] = (i < N_NODES) ? cnt[i] : 0;
    }
    int ts = v[0] + v[1] + v[2] + v[3];
    tsum[t] = ts;
    __syncthreads();
    for (int off = 1; off < 256; off <<= 1) {
        int add = (t >= off) ? tsum[t - off] : 0;
        __syncthreads();
        tsum[t] += add;
        __syncthreads();
    }
    int incl = tsum[t];
    int run = incl - ts;  // exclusive prefix for this thread
#pragma unroll
    for (int j = 0; j < 4; ++j) {
        int i = base + j;
        if (i < N_NODES) rp[i] = run;
        run += v[j];
    }
    if (t == 255) bsum[blockIdx.x] = incl;
}

__global__ void scan_bsums(int* __restrict__ bsum, int nblocks) {
    if (threadIdx.x == 0 && blockIdx.x == 0) {
        int run = 0;
        for (int b = 0; b < nblocks; ++b) {
            int v = bsum[b];
            bsum[b] = run;
            run += v;
        }
    }
}

__global__ void scan_add(int* __restrict__ rp, int* __restrict__ fill,
                         const int* __restrict__ bsum) {
    int add = bsum[blockIdx.x];
    int base = blockIdx.x * 1024;
#pragma unroll
    for (int j = 0; j < 4; ++j) {
        int i = base + j * 256 + threadIdx.x;
        if (i < N_NODES) {
            int v = rp[i] + add;
            rp[i] = v;
            fill[i] = v;
        }
    }
    if (blockIdx.x == 0 && threadIdx.x == 0) rp[N_NODES] = N_EDGES;
}

__global__ void fill_kernel(const int* __restrict__ edge, int* __restrict__ fill,
                            int* __restrict__ col) {
    int e = blockIdx.x * 256 + threadIdx.x;
    if (e < N_EDGES) {
        int dst = edge[N_EDGES + e];
        int slot = atomicAdd(&fill[dst], 1);
        col[slot] = edge[e];
    }
}

// ---------------- aggregation: S[v] = inv_deg * sum_{e: dst=v} h[src(e)] ----------------
__global__ __launch_bounds__(256) void agg_kernel(const float* __restrict__ h,
                                                  const int* __restrict__ rp,
                                                  const int* __restrict__ col,
                                                  float* __restrict__ S) {
    int w = threadIdx.x >> 6;
    int lane = threadIdx.x & 63;
    int v = blockIdx.x * 4 + w;
    if (v >= N_NODES) return;
    int beg = rp[v];
    int end = rp[v + 1];
    const float2* hp = (const float2*)h;
    float ax = 0.f, ay = 0.f;
    for (int j = beg; j < end; ++j) {
        int u = col[j];
        float2 t = hp[(size_t)u * 64 + lane];
        ax += t.x;
        ay += t.y;
    }
    float inv = 1.0f / fmaxf((float)(end - beg), 1.0f);
    float2 o;
    o.x = ax * inv;
    o.y = ay * inv;
    ((float2*)S)[(size_t)v * 64 + lane] = o;
}

// ---------------- fp32 GEMM: out = epilogue(A @ W^T + bias) ----------------
// MODE 0: out = A@W^T + bias                       (input projection)
// MODE 1: out = A@W^T + bias*(cnt[row]>0)          (message GEMM, in-place A==out)
// MODE 2: out = H + relu(A@W^T + bias)             (update GEMM, H==out in-place)
#define TR 64
template <int MODE>
__global__ __launch_bounds__(512, 1) void gemm_k(const float* __restrict__ A,
                                                 const float* __restrict__ W,
                                                 const float* __restrict__ bias,
                                                 const int* __restrict__ cnt,
                                                 const float* __restrict__ H,
                                                 float* __restrict__ out, int nrows) {
    extern __shared__ float smem[];
    float* Ws = smem;          // 128*128 floats, k4-index XOR-swizzled per row
    float* As = smem + 16384;  // TR*128 floats
    int t = threadIdx.x;
    int rowbase = blockIdx.x * TR;

    // stage W into LDS with XOR swizzle: element W[c][k4*4+j] at Ws[c*128 + (k4^((c>>2)&7))*4 + j]
#pragma unroll
    for (int ch = 0; ch < 8; ++ch) {
        int flat = t + ch * 512;  // float4 index, 0..4095
        int c = flat >> 5;
        int k4 = flat & 31;
        float4 w = ((const float4*)W)[c * 32 + k4];
        int kk = k4 ^ ((c >> 2) & 7);
        *((float4*)&Ws[c * 128 + kk * 4]) = w;
    }
    // stage A tile
#pragma unroll
    for (int ch = 0; ch < 4; ++ch) {
        int flat = t + ch * 512;  // float4 index, 0..2047
        int r = flat >> 5;
        int k4 = flat & 31;
        int gr = rowbase + r;
        float4 a = (gr < nrows) ? ((const float4*)A)[(size_t)gr * 32 + k4]
                                : make_float4(0.f, 0.f, 0.f, 0.f);
        *((float4*)&As[r * 128 + k4 * 4]) = a;
    }
    __syncthreads();

    int cg = t & 31;   // 32 column groups of 4 cols
    int rg = t >> 5;   // 16 row groups of 4 rows
    int c0 = cg * 4;
    int r0 = rg * 4;
    float4 acc[4];
#pragma unroll
    for (int i = 0; i < 4; ++i) acc[i] = make_float4(0.f, 0.f, 0.f, 0.f);

    int kksw = (cg & 7);  // (c>>2)&7 is cg for all 4 cols of this thread
#pragma unroll 4
    for (int k4 = 0; k4 < 32; ++k4) {
        int kk4 = (k4 ^ kksw) * 4;
        float4 w0 = *((const float4*)&Ws[(c0 + 0) * 128 + kk4]);
        float4 w1 = *((const float4*)&Ws[(c0 + 1) * 128 + kk4]);
        float4 w2 = *((const float4*)&Ws[(c0 + 2) * 128 + kk4]);
        float4 w3 = *((const float4*)&Ws[(c0 + 3) * 128 + kk4]);
#pragma unroll
        for (int i = 0; i < 4; ++i) {
            float4 a = *((const float4*)&As[(r0 + i) * 128 + k4 * 4]);
            acc[i].x = fmaf(a.x, w0.x, fmaf(a.y, w0.y, fmaf(a.z, w0.z, fmaf(a.w, w0.w, acc[i].x))));
            acc[i].y = fmaf(a.x, w1.x, fmaf(a.y, w1.y, fmaf(a.z, w1.z, fmaf(a.w, w1.w, acc[i].y))));
            acc[i].z = fmaf(a.x, w2.x, fmaf(a.y, w2.y, fmaf(a.z, w2.z, fmaf(a.w, w2.w, acc[i].z))));
            acc[i].w = fmaf(a.x, w3.x, fmaf(a.y, w3.y, fmaf(a.z, w3.z, fmaf(a.w, w3.w, acc[i].w))));
        }
    }

    float4 bv = ((const float4*)bias)[cg];
#pragma unroll
    for (int i = 0; i < 4; ++i) {
        int r = rowbase + r0 + i;
        if (r >= nrows) continue;
        float4 o = acc[i];
        if (MODE == 0) {
            o.x += bv.x; o.y += bv.y; o.z += bv.z; o.w += bv.w;
        } else if (MODE == 1) {
            float f = (cnt[r] > 0) ? 1.0f : 0.0f;
            o.x += bv.x * f; o.y += bv.y * f; o.z += bv.z * f; o.w += bv.w * f;
        } else {
            float4 hv = ((const float4*)H)[(size_t)r * 32 + cg];
            o.x = hv.x + fmaxf(o.x + bv.x, 0.f);
            o.y = hv.y + fmaxf(o.y + bv.y, 0.f);
            o.z = hv.z + fmaxf(o.z + bv.z, 0.f);
            o.w = hv.w + fmaxf(o.w + bv.w, 0.f);
        }
        ((float4*)out)[(size_t)r * 32 + cg] = o;
    }
}

extern "C" void kernel_launch(void* const* d_in, const int* in_sizes, int n_in,
                              void* d_out, int out_size, void* d_ws, size_t ws_size,
                              hipStream_t stream) {
    const float* x = (const float*)d_in[0];
    const float* Wi = (const float*)d_in[1];
    const float* bi = (const float*)d_in[2];
    const float* Wm = (const float*)d_in[3];
    const float* bm = (const float*)d_in[4];
    const float* Wu = (const float*)d_in[5];
    const float* bu = (const float*)d_in[6];
    const int* edge = (const int*)d_in[7];
    float* h = (float*)d_out;

    // workspace layout (256B aligned)
    char* ws = (char*)d_ws;
    size_t off = 0;
    auto alloc = [&](size_t bytes) {
        void* p = ws + off;
        off += (bytes + 255) & ~(size_t)255;
        return p;
    };
    float* S = (float*)alloc((size_t)N_NODES * D * sizeof(float));
    int* cnt = (int*)alloc((size_t)N_NODES * sizeof(int));
    int* rp = (int*)alloc((size_t)(N_NODES + 1) * sizeof(int));
    int* fill = (int*)alloc((size_t)N_NODES * sizeof(int));
    int* bsum = (int*)alloc(1024 * sizeof(int));
    int* col = (int*)alloc((size_t)N_EDGES * sizeof(int));

    const int scan_blocks = (N_NODES + 1023) / 1024;  // 98
    const int edge_blocks = (N_EDGES + 255) / 256;    // 2500
    const int gemm_blocks = (N_NODES + TR - 1) / TR;  // 1563
    const int agg_blocks = (N_NODES + 3) / 4;         // 25000
    const size_t gemm_lds = (16384 + TR * 128) * sizeof(float);  // 96 KiB

    // CSR build (per call; deterministic given inputs)
    hipMemsetAsync(cnt, 0, (size_t)N_NODES * sizeof(int), stream);
    count_kernel<<<edge_blocks, 256, 0, stream>>>(edge, cnt);
    scan_local<<<scan_blocks, 256, 0, stream>>>(cnt, rp, bsum);
    scan_bsums<<<1, 64, 0, stream>>>(bsum, scan_blocks);
    scan_add<<<scan_blocks, 256, 0, stream>>>(rp, fill, bsum);
    fill_kernel<<<edge_blocks, 256, 0, stream>>>(edge, fill, col);

    // input projection: h = x @ Wi^T + bi
    gemm_k<0><<<gemm_blocks, 512, gemm_lds, stream>>>(x, Wi, bi, nullptr, nullptr, h, N_NODES);

    for (int l = 0; l < NLAYERS; ++l) {
        agg_kernel<<<agg_blocks, 256, 0, stream>>>(h, rp, col, S);
        gemm_k<1><<<gemm_blocks, 512, gemm_lds, stream>>>(S, Wm + (size_t)l * D * D,
                                                          bm + (size_t)l * D, cnt, nullptr, S,
                                                          N_NODES);
        gemm_k<2><<<gemm_blocks, 512, gemm_lds, stream>>>(S, Wu + (size_t)l * D * D,
                                                          bu + (size_t)l * D, nullptr, h, h,
                                                          N_NODES);
    }
}